// Round 5
// baseline (178.876 us; speedup 1.0000x reference)
//
#include <hip/hip_runtime.h>
#include <math.h>

// QuanvolutionHybridGraphQL:
//   q   = cos(2x2 patches of 28x28 img)            -> (B,196,4)
//   qn  = q / (||q||_2 + 1e-12)
//   fid = (qn . qn^T)^2                             -> (B,196,196)
//   adj = fid>=0.8 ? 1 : fid>=0.5 ? 0.5 : 0 ; diag=0
//   logits = (mean_n q @ W1 + b1) @ W2 + b2         -> (B,10)
// Output = concat(logits flat, adj flat).
// adj is 629 MB fp32 -> HBM-write bound. Fill calibrates ~6.6 TB/s (~97us).
// R1 scalar stores 179us | R3 float4 NT 140us | R4 plain stores 150us
//   -> NT helps, keep it.
// R5: register-resident columns. Old loop read 80B LDS per 16B stored
// (LDS pipe ~171K cyc/CU vs 230K store-drain -> overlap pressure).
// Now lane l holds columns 4l..4l+3 in 16 VGPRs (loaded once); per row:
// one uniform ds_read_b128 broadcast + 16 FMA + NT store of 784B row seg.

#define NP   196
#define NPIX 784
#define BLK  256
#define VPR  (NP / 4)        // 49 float4 per row

typedef float f32x4 __attribute__((ext_vector_type(4)));

__global__ __launch_bounds__(BLK) void quanv_kernel(
    const float* __restrict__ x,
    const float* __restrict__ W1, const float* __restrict__ b1,
    const float* __restrict__ W2, const float* __restrict__ b2,
    float* __restrict__ logits, float* __restrict__ adj)
{
    __shared__ float q4[NP][4];                    // q, patch-major (pooled)
    __shared__ __align__(16) float qnA[NP][4];     // qn, patch-major AoS
    __shared__ float pooled[4];

    const int b   = blockIdx.x;
    const int tid = threadIdx.x;
    const int w   = tid >> 6;      // wave 0..3
    const int l   = tid & 63;      // lane 0..63
    const float* img = x + (size_t)b * NPIX;

    // 1) coalesced pixel load -> cos -> q in LDS
    for (int p = tid; p < NPIX; p += BLK) {
        int r = p / 28;
        int c = p - r * 28;
        int n  = (r >> 1) * 14 + (c >> 1);       // patch index
        int dd = ((r & 1) << 1) | (c & 1);       // element within patch
        q4[n][dd] = cosf(img[p]);
    }
    __syncthreads();

    // 2) per-patch L2-normalize (AoS layout)
    if (tid < NP) {
        float a0 = q4[tid][0], a1 = q4[tid][1], a2 = q4[tid][2], a3 = q4[tid][3];
        float inv = 1.0f / (sqrtf(a0*a0 + a1*a1 + a2*a2 + a3*a3) + 1e-12f);
        qnA[tid][0] = a0 * inv;
        qnA[tid][1] = a1 * inv;
        qnA[tid][2] = a2 * inv;
        qnA[tid][3] = a3 * inv;
    }

    // 3) pooled = mean_n q  (wave 0: partial sums + shuffle reduce)
    if (tid < 64) {
        float s0 = 0.f, s1 = 0.f, s2 = 0.f, s3 = 0.f;
        for (int n = tid; n < NP; n += 64) {
            s0 += q4[n][0]; s1 += q4[n][1]; s2 += q4[n][2]; s3 += q4[n][3];
        }
        #pragma unroll
        for (int off = 32; off >= 1; off >>= 1) {
            s0 += __shfl_down(s0, off);
            s1 += __shfl_down(s1, off);
            s2 += __shfl_down(s2, off);
            s3 += __shfl_down(s3, off);
        }
        if (tid == 0) {
            pooled[0] = s0 * (1.0f / NP);
            pooled[1] = s1 * (1.0f / NP);
            pooled[2] = s2 * (1.0f / NP);
            pooled[3] = s3 * (1.0f / NP);
        }
    }
    __syncthreads();

    // 4) tiny MLP: logits = (pooled @ W1 + b1) @ W2 + b2
    if (tid < 10) {
        float p0 = pooled[0], p1 = pooled[1], p2 = pooled[2], p3 = pooled[3];
        float acc = b2[tid];
        #pragma unroll
        for (int k = 0; k < 32; ++k) {
            float h = b1[k] + p0 * W1[0*32 + k] + p1 * W1[1*32 + k]
                            + p2 * W1[2*32 + k] + p3 * W1[3*32 + k];
            acc += h * W2[k*10 + tid];
        }
        logits[(size_t)b * 10 + tid] = acc;
    }

    // 5) adj: wave w owns rows 49w..49w+48; lane l owns columns 4l..4l+3.
    //    Column operands live in registers; per row one uniform LDS
    //    broadcast + 16 FMA + one NT float4 store (784B/row segment/wave).
    if (l < VPR) {
        const f32x4 p0 = *reinterpret_cast<const f32x4*>(&qnA[4*l + 0][0]);
        const f32x4 p1 = *reinterpret_cast<const f32x4*>(&qnA[4*l + 1][0]);
        const f32x4 p2 = *reinterpret_cast<const f32x4*>(&qnA[4*l + 2][0]);
        const f32x4 p3 = *reinterpret_cast<const f32x4*>(&qnA[4*l + 3][0]);
        const int col0 = 4*l;

        f32x4* outb = reinterpret_cast<f32x4*>(adj + (size_t)b * (NP * NP));
        const int nEnd = VPR * (w + 1);
        for (int n = VPR * w; n < nEnd; ++n) {
            f32x4 c = *reinterpret_cast<const f32x4*>(&qnA[n][0]); // broadcast
            f32x4 d;
            d.x = c.x*p0.x + c.y*p0.y + c.z*p0.z + c.w*p0.w;
            d.y = c.x*p1.x + c.y*p1.y + c.z*p1.z + c.w*p1.w;
            d.z = c.x*p2.x + c.y*p2.y + c.z*p2.z + c.w*p2.w;
            d.w = c.x*p3.x + c.y*p3.y + c.z*p3.z + c.w*p3.w;
            f32x4 f = d * d;

            f32x4 o;
            o.x = (f.x >= 0.8f) ? 1.0f : ((f.x >= 0.5f) ? 0.5f : 0.0f);
            o.y = (f.y >= 0.8f) ? 1.0f : ((f.y >= 0.5f) ? 0.5f : 0.0f);
            o.z = (f.z >= 0.8f) ? 1.0f : ((f.z >= 0.5f) ? 0.5f : 0.0f);
            o.w = (f.w >= 0.8f) ? 1.0f : ((f.w >= 0.5f) ? 0.5f : 0.0f);

            // zero the diagonal element (column n) if it's in this lane
            o.x = (col0 + 0 == n) ? 0.0f : o.x;
            o.y = (col0 + 1 == n) ? 0.0f : o.y;
            o.z = (col0 + 2 == n) ? 0.0f : o.z;
            o.w = (col0 + 3 == n) ? 0.0f : o.w;

            __builtin_nontemporal_store(o, &outb[n * VPR + l]);
        }
    }
}

extern "C" void kernel_launch(void* const* d_in, const int* in_sizes, int n_in,
                              void* d_out, int out_size, void* d_ws, size_t ws_size,
                              hipStream_t stream) {
    const float* x  = (const float*)d_in[0];
    const float* W1 = (const float*)d_in[1];
    const float* b1 = (const float*)d_in[2];
    const float* W2 = (const float*)d_in[3];
    const float* b2 = (const float*)d_in[4];

    const int B = in_sizes[0] / NPIX;          // 4096
    float* logits = (float*)d_out;             // B*10
    float* adj    = logits + (size_t)B * 10;   // B*196*196

    quanv_kernel<<<B, BLK, 0, stream>>>(x, W1, b1, W2, b2, logits, adj);
}

// Round 7
// 137.514 us; speedup vs baseline: 1.3008x; 1.3008x over previous
//
#include <hip/hip_runtime.h>
#include <math.h>

// QuanvolutionHybridGraphQL:
//   q   = cos(2x2 patches of 28x28 img)            -> (B,196,4)
//   qn  = q / (||q||_2 + 1e-12)
//   fid = (qn . qn^T)^2                             -> (B,196,196)
//   adj = fid>=0.8 ? 1 : fid>=0.5 ? 0.5 : 0 ; diag=0
//   logits = (mean_n q @ W1 + b1) @ W2 + b2         -> (B,10)
// adj is 629 MB fp32 -> HBM-write bound. Fill calibrates ~6.8 TB/s (~97us).
// Store-shape ladder: 256B/inst=179us | 784B misaligned=179us |
// 1KiB half-misaligned (R3)=140us. Partial cachelines cost superlinearly.
// R6/R7: image PAIR per block. 2 slabs = 307,328B = exactly 2401 lines,
// so every wave's 1KiB NT store is globally 128B-aligned (tail: one
// aligned 128B store). Grid 2048 = exactly 8 blocks/CU, single round.
// R7 fixes R6's bug: normalize step guarded tid<392 with only 256 threads
// -> image-1 patches n>=60 were garbage. Now a strided loop.

#define NP    196
#define NPIX  784
#define BLK   256
#define VPR   (NP / 4)            // 49 float4 per row
#define F4PI  (NP * NP / 4)       // 9604 float4 per image
#define F4PP  (2 * F4PI)          // 19208 float4 per image pair

typedef float f32x4 __attribute__((ext_vector_type(4)));

__global__ __launch_bounds__(BLK) void quanv_kernel(
    const float* __restrict__ x,
    const float* __restrict__ W1, const float* __restrict__ b1,
    const float* __restrict__ W2, const float* __restrict__ b2,
    float* __restrict__ logits, float* __restrict__ adj)
{
    __shared__ float q4[2][NP][4];                   // q, patch-major
    __shared__ __align__(16) float qnT[2][4][NP];    // qn, dim-major
    __shared__ float pooled[2][4];

    const int g   = blockIdx.x;        // image pair index
    const int tid = threadIdx.x;
    const int w   = tid >> 6;          // wave 0..3
    const int l   = tid & 63;          // lane 0..63
    const float* imgs = x + (size_t)g * (2 * NPIX);

    // 1) coalesced pixel load (both images) -> cos -> q in LDS
    for (int p = tid; p < 2 * NPIX; p += BLK) {
        int im = (p >= NPIX);
        int pp = p - im * NPIX;
        int r = pp / 28;
        int c = pp - r * 28;
        int n  = (r >> 1) * 14 + (c >> 1);
        int dd = ((r & 1) << 1) | (c & 1);
        q4[im][n][dd] = cosf(imgs[p]);
    }
    __syncthreads();

    // 2) per-patch L2-normalize into dim-major layout (both images).
    //    NOTE: 392 patches > 256 threads -> MUST be a strided loop.
    for (int t = tid; t < 2 * NP; t += BLK) {
        int im = (t >= NP);
        int n  = t - im * NP;
        float a0 = q4[im][n][0], a1 = q4[im][n][1];
        float a2 = q4[im][n][2], a3 = q4[im][n][3];
        float inv = 1.0f / (sqrtf(a0*a0 + a1*a1 + a2*a2 + a3*a3) + 1e-12f);
        qnT[im][0][n] = a0 * inv;
        qnT[im][1][n] = a1 * inv;
        qnT[im][2][n] = a2 * inv;
        qnT[im][3][n] = a3 * inv;
    }

    // 3) pooled = mean_n q  (wave 0 -> image 0, wave 1 -> image 1)
    if (w < 2) {
        float s0 = 0.f, s1 = 0.f, s2 = 0.f, s3 = 0.f;
        for (int n = l; n < NP; n += 64) {
            s0 += q4[w][n][0]; s1 += q4[w][n][1];
            s2 += q4[w][n][2]; s3 += q4[w][n][3];
        }
        #pragma unroll
        for (int off = 32; off >= 1; off >>= 1) {
            s0 += __shfl_down(s0, off);
            s1 += __shfl_down(s1, off);
            s2 += __shfl_down(s2, off);
            s3 += __shfl_down(s3, off);
        }
        if (l == 0) {
            pooled[w][0] = s0 * (1.0f / NP);
            pooled[w][1] = s1 * (1.0f / NP);
            pooled[w][2] = s2 * (1.0f / NP);
            pooled[w][3] = s3 * (1.0f / NP);
        }
    }
    __syncthreads();

    // 4) tiny MLP for both images: threads 0..9 -> im 0, 10..19 -> im 1
    if (tid < 20) {
        int im = (tid >= 10);
        int j  = tid - im * 10;
        float p0 = pooled[im][0], p1 = pooled[im][1];
        float p2 = pooled[im][2], p3 = pooled[im][3];
        float acc = b2[j];
        #pragma unroll
        for (int k = 0; k < 32; ++k) {
            float h = b1[k] + p0 * W1[0*32 + k] + p1 * W1[1*32 + k]
                            + p2 * W1[2*32 + k] + p3 * W1[3*32 + k];
            acc += h * W2[k*10 + j];
        }
        logits[(size_t)(2*g + im) * 10 + j] = acc;
    }

    // 5) adj for the pair: flat loop, every wave store = aligned 1KiB NT.
    f32x4* outp = reinterpret_cast<f32x4*>(adj) + (size_t)g * F4PP;
    for (int e4 = tid; e4 < F4PP; e4 += BLK) {
        int im  = (e4 >= F4PI);
        int rem = e4 - im * F4PI;
        int n   = rem / VPR;               // magic-div by 49
        int m0  = (rem - n * VPR) * 4;

        float c0 = qnT[im][0][n], c1 = qnT[im][1][n];
        float c2 = qnT[im][2][n], c3 = qnT[im][3][n];
        f32x4 v0 = *reinterpret_cast<const f32x4*>(&qnT[im][0][m0]);
        f32x4 v1 = *reinterpret_cast<const f32x4*>(&qnT[im][1][m0]);
        f32x4 v2 = *reinterpret_cast<const f32x4*>(&qnT[im][2][m0]);
        f32x4 v3 = *reinterpret_cast<const f32x4*>(&qnT[im][3][m0]);

        f32x4 d = c0*v0 + c1*v1 + c2*v2 + c3*v3;
        f32x4 f = d * d;

        f32x4 o;
        o.x = (f.x >= 0.8f) ? 1.0f : ((f.x >= 0.5f) ? 0.5f : 0.0f);
        o.y = (f.y >= 0.8f) ? 1.0f : ((f.y >= 0.5f) ? 0.5f : 0.0f);
        o.z = (f.z >= 0.8f) ? 1.0f : ((f.z >= 0.5f) ? 0.5f : 0.0f);
        o.w = (f.w >= 0.8f) ? 1.0f : ((f.w >= 0.5f) ? 0.5f : 0.0f);

        // zero the diagonal element (column n) if it's in this float4
        o.x = (m0 + 0 == n) ? 0.0f : o.x;
        o.y = (m0 + 1 == n) ? 0.0f : o.y;
        o.z = (m0 + 2 == n) ? 0.0f : o.z;
        o.w = (m0 + 3 == n) ? 0.0f : o.w;

        __builtin_nontemporal_store(o, &outp[e4]);
    }
}

extern "C" void kernel_launch(void* const* d_in, const int* in_sizes, int n_in,
                              void* d_out, int out_size, void* d_ws, size_t ws_size,
                              hipStream_t stream) {
    const float* x  = (const float*)d_in[0];
    const float* W1 = (const float*)d_in[1];
    const float* b1 = (const float*)d_in[2];
    const float* W2 = (const float*)d_in[3];
    const float* b2 = (const float*)d_in[4];

    const int B = in_sizes[0] / NPIX;          // 4096
    float* logits = (float*)d_out;             // B*10
    float* adj    = logits + (size_t)B * 10;   // B*196*196

    quanv_kernel<<<B / 2, BLK, 0, stream>>>(x, W1, b1, W2, b2, logits, adj);
}